// Round 9
// baseline (116.143 us; speedup 1.0000x reference)
//
#include <hip/hip_runtime.h>
#include <hip/hip_bf16.h>

#define BLK 256
#define CH 8

// Quaternion (.x=w, .y=v1, .z=v2, .w=v3) representing SU(2) matrix w*I - i*(v.sigma)
// with sigma = (pauli0, pauli1, pauli2) from the reference; e_a = -i*sigma_a satisfy
// the quaternion algebra, so Hamilton product == matrix product.
// qmul(A,B) == A@B (A is the LATER factor).
__device__ __forceinline__ float4 qmul(const float4 A, const float4 B) {
    return make_float4(
        A.x*B.x - A.y*B.y - A.z*B.z - A.w*B.w,
        A.x*B.y + B.x*A.y + A.z*B.w - A.w*B.z,
        A.x*B.z + B.x*A.z + A.w*B.y - A.y*B.w,
        A.x*B.w + B.x*A.w + A.y*B.z - A.z*B.y);
}

__device__ __forceinline__ float4 qid() { return make_float4(1.f, 0.f, 0.f, 0.f); }

__device__ __forceinline__ float4 qnorm(const float4 q) {
    float n = rsqrtf(q.x*q.x + q.y*q.y + q.z*q.z + q.w*q.w);
    return make_float4(q.x*n, q.y*n, q.z*n, q.w*n);
}

// Per-step rotation quat: al = 0.01*alpha, theta=|al|, quat=(cos th, sinc(th)*al).
// theta <= ~0.07 here, so 4th-order Taylor is exact to ~1e-10.
__device__ __forceinline__ float4 dquat(float a0, float a1, float a2) {
    float x = a0 * 0.01f, y = a1 * 0.01f, z = a2 * 0.01f;
    float t2 = x*x + y*y + z*z;
    float c = 1.f - t2 * (0.5f - t2 * (1.f / 24.f));
    float f = 1.f - t2 * ((1.f / 6.f) - t2 * (1.f / 120.f));
    return make_float4(c, f*x, f*y, f*z);
}

// Apply M (quat) to complex 2-vector; returns (re0, im0, re1, im1).
// M = [[w - i v1, -v3 - i v2],[v3 - i v2, w + i v1]]
__device__ __forceinline__ float4 qapply(const float4 m, float s0r, float s1r,
                                         float s0i, float s1i) {
    float w = m.x, v1 = m.y, v2 = m.z, v3 = m.w;
    return make_float4(
        w*s0r + v1*s0i - v3*s1r + v2*s1i,
        w*s0i - v1*s0r - v2*s1r - v3*s1i,
        v3*s0r + v2*s0i + w*s1r - v1*s1i,
        v3*s0i - v2*s0r + w*s1i + v1*s1r);
}

// In-order Hillis-Steele inclusive scan across the block (op: later@earlier).
// On return sh[] holds inclusive values (last op is a barrier; no later writes).
__device__ __forceinline__ float4 block_scan_incl(float4 v, float4* sh) {
    const int tid = threadIdx.x;
    sh[tid] = v;
    __syncthreads();
    #pragma unroll
    for (int d = 1; d < BLK; d <<= 1) {
        float4 other;
        bool act = tid >= d;
        if (act) other = sh[tid - d];
        __syncthreads();
        if (act) { v = qmul(v, other); sh[tid] = v; }
        __syncthreads();
    }
    return v;
}

// Wave-ordered descending product: lane 0 receives c[63] @ c[62] @ ... @ c[0].
// (Tree combine: segment [i, i+2s) = seg[i+s,i+2s) @ seg[i,i+s); higher lane = LEFT.)
__device__ __forceinline__ float4 wave_prod_desc(float4 c) {
    #pragma unroll
    for (int s = 1; s < 64; s <<= 1) {
        float4 u;
        u.x = __shfl_down(c.x, s); u.y = __shfl_down(c.y, s);
        u.z = __shfl_down(c.z, s); u.w = __shfl_down(c.w, s);
        c = qmul(u, c);
    }
    return c;
}

// Compute the CH per-step quats d[] and their chunk product (d[CH-1]@...@d[0]).
__device__ __forceinline__ float4 chunk_quats(const float* __restrict__ al,
                                              long long t, long long T,
                                              long long nchunk, float4* d, bool& full) {
    float4 q = qid();
    full = false;
    if (t >= nchunk) {
        #pragma unroll
        for (int j = 0; j < CH; ++j) d[j] = qid();
        return q;
    }
    if ((t + 1) * CH <= T) {
        full = true;
        const float4* ap = reinterpret_cast<const float4*>(al) + (size_t)t * 6;
        float4 v0 = ap[0], v1 = ap[1], v2 = ap[2];
        float4 v3 = ap[3], v4 = ap[4], v5 = ap[5];
        d[0] = dquat(v0.x, v0.y, v0.z);
        d[1] = dquat(v0.w, v1.x, v1.y);
        d[2] = dquat(v1.z, v1.w, v2.x);
        d[3] = dquat(v2.y, v2.z, v2.w);
        d[4] = dquat(v3.x, v3.y, v3.z);
        d[5] = dquat(v3.w, v4.x, v4.y);
        d[6] = dquat(v4.z, v4.w, v5.x);
        d[7] = dquat(v5.y, v5.z, v5.w);
    } else {
        #pragma unroll
        for (int j = 0; j < CH; ++j) {
            long long k = t * CH + j;
            d[j] = (k < T) ? dquat(al[k*3], al[k*3+1], al[k*3+2]) : qid();
        }
    }
    #pragma unroll
    for (int j = 0; j < CH; ++j) q = qmul(d[j], q);
    return qnorm(q);
}

// Epilogue. OUTPUT: float32, real parts only, [T,2] row-major:
// outf[2k] = Re(out0(k)), outf[2k+1] = Re(out1(k)).
__device__ __forceinline__ void apply_and_store(
    const float4* d, float4 run, bool full, long long t, long long T,
    const float* __restrict__ sre, const float* __restrict__ sim,
    float* __restrict__ outf) {
    if (full) {
        const float4* rp = reinterpret_cast<const float4*>(sre) + (size_t)t * 4;
        const float4* ip = reinterpret_cast<const float4*>(sim) + (size_t)t * 4;
        float4* op = reinterpret_cast<float4*>(outf) + (size_t)t * 4;
        float4 r0 = rp[0], r1 = rp[1], r2 = rp[2], r3 = rp[3];
        float4 i0 = ip[0], i1 = ip[1], i2 = ip[2], i3 = ip[3];
        float4 p0, p1;
        run = qmul(d[0], run); p0 = qapply(run, r0.x, r0.y, i0.x, i0.y);
        run = qmul(d[1], run); p1 = qapply(run, r0.z, r0.w, i0.z, i0.w);
        op[0] = make_float4(p0.x, p0.z, p1.x, p1.z);
        run = qmul(d[2], run); p0 = qapply(run, r1.x, r1.y, i1.x, i1.y);
        run = qmul(d[3], run); p1 = qapply(run, r1.z, r1.w, i1.z, i1.w);
        op[1] = make_float4(p0.x, p0.z, p1.x, p1.z);
        run = qmul(d[4], run); p0 = qapply(run, r2.x, r2.y, i2.x, i2.y);
        run = qmul(d[5], run); p1 = qapply(run, r2.z, r2.w, i2.z, i2.w);
        op[2] = make_float4(p0.x, p0.z, p1.x, p1.z);
        run = qmul(d[6], run); p0 = qapply(run, r3.x, r3.y, i3.x, i3.y);
        run = qmul(d[7], run); p1 = qapply(run, r3.z, r3.w, i3.z, i3.w);
        op[3] = make_float4(p0.x, p0.z, p1.x, p1.z);
    } else {
        float2* op2 = reinterpret_cast<float2*>(outf);
        #pragma unroll
        for (int j = 0; j < CH; ++j) {
            long long k = t * CH + j;
            if (k < T) {
                run = qmul(d[j], run);
                float4 p = qapply(run, sre[k*2], sre[k*2+1], sim[k*2], sim[k*2+1]);
                op2[k] = make_float2(p.x, p.z);
            }
        }
    }
}

// Zero flags + ticket before the fused kernel (same stream => ordered).
__global__ void __launch_bounds__(BLK) pmd_init(unsigned* __restrict__ flags, int n) {
    int i = blockIdx.x * BLK + threadIdx.x;
    if (i < n) flags[i] = 0u;
}

// Single fused pass: reduce-then-scan with device-scope flags.
// rank via atomic ticket => a block only waits on lower ranks (started earlier)
// => no deadlock at any occupancy. Spine composition uses FIXED 64-wide windows
// over aggregates only => bitwise-deterministic output.
__global__ void __launch_bounds__(BLK) pmd_fused(
    const float* __restrict__ al, const float* __restrict__ sre,
    const float* __restrict__ sim, const float* __restrict__ j0re,
    const float* __restrict__ j0im, float* __restrict__ outf,
    float4* __restrict__ Aarr, unsigned* __restrict__ flags,
    unsigned* __restrict__ ticket, long long T, long long nchunk) {
    __shared__ float4 sh[BLK];
    __shared__ unsigned srank;
    __shared__ float4 sexcl;
    const int tid = threadIdx.x;
    if (tid == 0) srank = atomicAdd(ticket, 1u);
    __syncthreads();
    const int rank = (int)srank;
    const long long t = (long long)rank * BLK + tid;

    float4 d[CH];
    bool full;
    float4 q = chunk_quats(al, t, T, nchunk, d, full);
    block_scan_incl(q, sh);
    float4 Xv = (tid == 0) ? qid() : sh[tid - 1];

    // Publish this block's aggregate ASAP (release so data precedes flag).
    if (tid == 0) {
        Aarr[rank] = qnorm(sh[BLK - 1]);
        __hip_atomic_store(&flags[rank], 1u, __ATOMIC_RELEASE,
                           __HIP_MEMORY_SCOPE_AGENT);
        if (rank == 0) {
            // q0 from J0 = [[w - i v1, -v3 - i v2],[v3 - i v2, w + i v1]]
            sexcl = make_float4(j0re[0], -j0im[0], -j0im[1], -j0re[1]);
        }
    }
    // Wave 0 composes the exclusive spine prefix from aggregates [0, rank).
    if (rank > 0 && tid < 64) {
        float4 excl = qid();
        int top = rank - 1;
        int base = (top >> 6) << 6;
        for (;;) {
            int j = base + tid;
            float4 contrib = qid();
            if (j <= top) {
                unsigned f;
                do {
                    f = __hip_atomic_load(&flags[j], __ATOMIC_ACQUIRE,
                                          __HIP_MEMORY_SCOPE_AGENT);
                } while (f == 0u);
                contrib = Aarr[j];
            }
            float4 wp = wave_prod_desc(contrib);  // lane 0: A[top]@...@A[base]
            excl = qmul(excl, wp);
            if (base == 0) break;
            top = base - 1;
            base -= 64;
        }
        if (tid == 0) {
            float4 q0 = make_float4(j0re[0], -j0im[0], -j0im[1], -j0re[1]);
            sexcl = qnorm(qmul(excl, q0));
        }
    }
    __syncthreads();
    float4 run = qmul(Xv, sexcl);
    apply_and_store(d, run, full, t, T, sre, sim, outf);
}

// Zero-workspace fallback: one block walks the whole sequence in segments.
__global__ void __launch_bounds__(BLK) pmd_mono(
    const float* __restrict__ al, const float* __restrict__ sre,
    const float* __restrict__ sim, const float* __restrict__ j0re,
    const float* __restrict__ j0im, float* __restrict__ outf, long long T) {
    __shared__ float4 sh[BLK];
    __shared__ float4 sbase;
    if (threadIdx.x == 0)
        sbase = make_float4(j0re[0], -j0im[0], -j0im[1], -j0re[1]);
    __syncthreads();
    const long long nchunk = (T + CH - 1) / CH;
    for (long long c0 = 0; c0 < nchunk; c0 += BLK) {
        const long long t = c0 + threadIdx.x;
        float4 d[CH];
        bool full;
        float4 q = chunk_quats(al, t, T, nchunk, d, full);
        float4 incl = block_scan_incl(q, sh);
        float4 Xv = (threadIdx.x == 0) ? qid() : sh[threadIdx.x - 1];
        float4 base = sbase;
        __syncthreads();
        if (threadIdx.x == BLK - 1) sbase = qnorm(qmul(incl, base));
        if (t < nchunk) {
            float4 run = qmul(Xv, base);
            apply_and_store(d, run, full, t, T, sre, sim, outf);
        }
        __syncthreads();
    }
}

extern "C" void kernel_launch(void* const* d_in, const int* in_sizes, int n_in,
                              void* d_out, int out_size, void* d_ws, size_t ws_size,
                              hipStream_t stream) {
    const float* sre  = (const float*)d_in[0];
    const float* sim  = (const float*)d_in[1];
    const float* al   = (const float*)d_in[2];
    const float* j0re = (const float*)d_in[3];
    const float* j0im = (const float*)d_in[4];
    float* outf = (float*)d_out;   // f32 out, real parts [T,2]
    long long T = (long long)in_sizes[2] / 3;
    if (T <= 0) return;

    long long nchunk = (T + CH - 1) / CH;
    long long nblkLL = (nchunk + BLK - 1) / BLK;
    // ws: Aarr[nblk] float4 | flags[nblk] u32 | ticket u32
    size_t need = (size_t)nblkLL * 16 + (size_t)(nblkLL + 1) * 4;

    if (ws_size >= need && nblkLL <= (1LL << 30)) {
        int nblk = (int)nblkLL;
        float4* Aarr = (float4*)d_ws;
        unsigned* flags = (unsigned*)((char*)d_ws + (size_t)nblk * 16);
        unsigned* ticket = flags + nblk;
        int ninit = nblk + 1;
        pmd_init<<<(ninit + BLK - 1) / BLK, BLK, 0, stream>>>(flags, ninit);
        pmd_fused<<<nblk, BLK, 0, stream>>>(al, sre, sim, j0re, j0im, outf,
                                            Aarr, flags, ticket, T, nchunk);
    } else {
        pmd_mono<<<1, BLK, 0, stream>>>(al, sre, sim, j0re, j0im, outf, T);
    }
}

// Round 10
// 34.707 us; speedup vs baseline: 3.3464x; 3.3464x over previous
//
#include <hip/hip_runtime.h>
#include <hip/hip_bf16.h>

#define BLK 256
#define CH 8

// Quaternion (.x=w, .y=v1, .z=v2, .w=v3) representing SU(2) matrix w*I - i*(v.sigma)
// with sigma = (pauli0, pauli1, pauli2) from the reference; e_a = -i*sigma_a satisfy
// the quaternion algebra, so Hamilton product == matrix product.
// qmul(A,B) == A@B (A is the LATER factor).
__device__ __forceinline__ float4 qmul(const float4 A, const float4 B) {
    return make_float4(
        A.x*B.x - A.y*B.y - A.z*B.z - A.w*B.w,
        A.x*B.y + B.x*A.y + A.z*B.w - A.w*B.z,
        A.x*B.z + B.x*A.z + A.w*B.y - A.y*B.w,
        A.x*B.w + B.x*A.w + A.y*B.z - A.z*B.y);
}

__device__ __forceinline__ float4 qid() { return make_float4(1.f, 0.f, 0.f, 0.f); }

__device__ __forceinline__ float4 qnorm(const float4 q) {
    float n = rsqrtf(q.x*q.x + q.y*q.y + q.z*q.z + q.w*q.w);
    return make_float4(q.x*n, q.y*n, q.z*n, q.w*n);
}

// Per-step rotation quat: al = 0.01*alpha, theta=|al|, quat=(cos th, sinc(th)*al).
// theta <= ~0.07 here, so 4th-order Taylor is exact to ~1e-10.
__device__ __forceinline__ float4 dquat(float a0, float a1, float a2) {
    float x = a0 * 0.01f, y = a1 * 0.01f, z = a2 * 0.01f;
    float t2 = x*x + y*y + z*z;
    float c = 1.f - t2 * (0.5f - t2 * (1.f / 24.f));
    float f = 1.f - t2 * ((1.f / 6.f) - t2 * (1.f / 120.f));
    return make_float4(c, f*x, f*y, f*z);
}

// Apply M (quat) to complex 2-vector; returns (re0, im0, re1, im1).
// M = [[w - i v1, -v3 - i v2],[v3 - i v2, w + i v1]]
__device__ __forceinline__ float4 qapply(const float4 m, float s0r, float s1r,
                                         float s0i, float s1i) {
    float w = m.x, v1 = m.y, v2 = m.z, v3 = m.w;
    return make_float4(
        w*s0r + v1*s0i - v3*s1r + v2*s1i,
        w*s0i - v1*s0r - v2*s1r - v3*s1i,
        v3*s0r + v2*s0i + w*s1r - v1*s1i,
        v3*s0i - v2*s0r + w*s1i + v1*s1r);
}

__device__ __forceinline__ float4 shfl_up4(const float4 v, int s) {
    return make_float4(__shfl_up(v.x, s), __shfl_up(v.y, s),
                       __shfl_up(v.z, s), __shfl_up(v.w, s));
}
__device__ __forceinline__ float4 shfl_down4(const float4 v, int s) {
    return make_float4(__shfl_down(v.x, s), __shfl_down(v.y, s),
                       __shfl_down(v.z, s), __shfl_down(v.w, s));
}

// Wave-ordered descending product: lane 0 receives c[63] @ c[62] @ ... @ c[0].
__device__ __forceinline__ float4 wave_prod_desc(float4 c) {
    #pragma unroll
    for (int s = 1; s < 64; s <<= 1) {
        float4 u = shfl_down4(c, s);
        c = qmul(u, c);   // segment = upper-half @ lower-half
    }
    return c;
}

// Wave-level INCLUSIVE ordered scan: lane l ends with c[l]@...@c[0].
__device__ __forceinline__ float4 wave_scan_incl(float4 v, int lane) {
    #pragma unroll
    for (int s = 1; s < 64; s <<= 1) {
        float4 u = shfl_up4(v, s);
        if (lane >= s) v = qmul(v, u);
    }
    return v;
}

// Chunk product only (no d[] retention) — for K1.
__device__ __forceinline__ float4 chunk_prod(const float* __restrict__ al,
                                             long long t, long long T,
                                             long long nchunk) {
    if (t >= nchunk) return qid();
    float4 q = qid();
    if ((t + 1) * CH <= T) {
        const float4* ap = reinterpret_cast<const float4*>(al) + (size_t)t * 6;
        float4 v0 = ap[0], v1 = ap[1], v2 = ap[2];
        float4 v3 = ap[3], v4 = ap[4], v5 = ap[5];
        q = dquat(v0.x, v0.y, v0.z);
        q = qmul(dquat(v0.w, v1.x, v1.y), q);
        q = qmul(dquat(v1.z, v1.w, v2.x), q);
        q = qmul(dquat(v2.y, v2.z, v2.w), q);
        q = qmul(dquat(v3.x, v3.y, v3.z), q);
        q = qmul(dquat(v3.w, v4.x, v4.y), q);
        q = qmul(dquat(v4.z, v4.w, v5.x), q);
        q = qmul(dquat(v5.y, v5.z, v5.w), q);
    } else {
        for (int j = 0; j < CH; ++j) {
            long long k = t * CH + j;
            if (k < T) q = qmul(dquat(al[k*3], al[k*3+1], al[k*3+2]), q);
        }
    }
    return qnorm(q);
}

// Chunk quats kept in registers + product — for K2.
__device__ __forceinline__ float4 chunk_quats(const float* __restrict__ al,
                                              long long t, long long T,
                                              long long nchunk, float4* d, bool& full) {
    float4 q = qid();
    full = false;
    if (t >= nchunk) {
        #pragma unroll
        for (int j = 0; j < CH; ++j) d[j] = qid();
        return q;
    }
    if ((t + 1) * CH <= T) {
        full = true;
        const float4* ap = reinterpret_cast<const float4*>(al) + (size_t)t * 6;
        float4 v0 = ap[0], v1 = ap[1], v2 = ap[2];
        float4 v3 = ap[3], v4 = ap[4], v5 = ap[5];
        d[0] = dquat(v0.x, v0.y, v0.z);
        d[1] = dquat(v0.w, v1.x, v1.y);
        d[2] = dquat(v1.z, v1.w, v2.x);
        d[3] = dquat(v2.y, v2.z, v2.w);
        d[4] = dquat(v3.x, v3.y, v3.z);
        d[5] = dquat(v3.w, v4.x, v4.y);
        d[6] = dquat(v4.z, v4.w, v5.x);
        d[7] = dquat(v5.y, v5.z, v5.w);
    } else {
        #pragma unroll
        for (int j = 0; j < CH; ++j) {
            long long k = t * CH + j;
            d[j] = (k < T) ? dquat(al[k*3], al[k*3+1], al[k*3+2]) : qid();
        }
    }
    #pragma unroll
    for (int j = 0; j < CH; ++j) q = qmul(d[j], q);
    return qnorm(q);
}

// Epilogue. OUTPUT: float32, real parts only, [T,2] row-major:
// outf[2k] = Re(out0(k)), outf[2k+1] = Re(out1(k)).
__device__ __forceinline__ void apply_and_store(
    const float4* d, float4 run, bool full, long long t, long long T,
    const float* __restrict__ sre, const float* __restrict__ sim,
    float* __restrict__ outf) {
    if (full) {
        const float4* rp = reinterpret_cast<const float4*>(sre) + (size_t)t * 4;
        const float4* ip = reinterpret_cast<const float4*>(sim) + (size_t)t * 4;
        float4* op = reinterpret_cast<float4*>(outf) + (size_t)t * 4;
        float4 r0 = rp[0], r1 = rp[1], r2 = rp[2], r3 = rp[3];
        float4 i0 = ip[0], i1 = ip[1], i2 = ip[2], i3 = ip[3];
        float4 p0, p1;
        run = qmul(d[0], run); p0 = qapply(run, r0.x, r0.y, i0.x, i0.y);
        run = qmul(d[1], run); p1 = qapply(run, r0.z, r0.w, i0.z, i0.w);
        op[0] = make_float4(p0.x, p0.z, p1.x, p1.z);
        run = qmul(d[2], run); p0 = qapply(run, r1.x, r1.y, i1.x, i1.y);
        run = qmul(d[3], run); p1 = qapply(run, r1.z, r1.w, i1.z, i1.w);
        op[1] = make_float4(p0.x, p0.z, p1.x, p1.z);
        run = qmul(d[4], run); p0 = qapply(run, r2.x, r2.y, i2.x, i2.y);
        run = qmul(d[5], run); p1 = qapply(run, r2.z, r2.w, i2.z, i2.w);
        op[2] = make_float4(p0.x, p0.z, p1.x, p1.z);
        run = qmul(d[6], run); p0 = qapply(run, r3.x, r3.y, i3.x, i3.y);
        run = qmul(d[7], run); p1 = qapply(run, r3.z, r3.w, i3.z, i3.w);
        op[3] = make_float4(p0.x, p0.z, p1.x, p1.z);
    } else {
        float2* op2 = reinterpret_cast<float2*>(outf);
        #pragma unroll
        for (int j = 0; j < CH; ++j) {
            long long k = t * CH + j;
            if (k < T) {
                run = qmul(d[j], run);
                float4 p = qapply(run, sre[k*2], sre[k*2+1], sim[k*2], sim[k*2+1]);
                op2[k] = make_float2(p.x, p.z);
            }
        }
    }
}

// K1: per-block aggregate via wave shfl-tree reduce (no Hillis-Steele, 1 barrier).
__global__ void __launch_bounds__(BLK) pmd_k1(
    const float* __restrict__ al, float4* __restrict__ A,
    long long T, long long nchunk) {
    __shared__ float4 sW[BLK / 64];
    const int tid = threadIdx.x, lane = tid & 63, wid = tid >> 6;
    const long long t = (long long)blockIdx.x * BLK + tid;
    float4 q = chunk_prod(al, t, T, nchunk);
    float4 wp = wave_prod_desc(q);
    if (lane == 0) sW[wid] = wp;
    __syncthreads();
    if (tid == 0) {
        float4 a = qmul(sW[1], sW[0]);
        a = qmul(sW[2], a);
        a = qmul(sW[3], a);
        A[blockIdx.x] = qnorm(a);
    }
}

// K2: per-block — wave 0 re-derives the spine prefix A[b-1]@...@A[0] from the
// aggregates (deterministic fixed 64-wide windows; A visible via kernel boundary,
// no flags/spins); all threads do an in-register wave scan for the in-block
// exclusive prefix; single barrier; epilogue.
__global__ void __launch_bounds__(BLK) pmd_k2(
    const float* __restrict__ al, const float* __restrict__ sre,
    const float* __restrict__ sim, const float* __restrict__ j0re,
    const float* __restrict__ j0im, const float4* __restrict__ A,
    float* __restrict__ outf, long long T, long long nchunk) {
    __shared__ float4 sW[BLK / 64];
    __shared__ float4 sexcl;
    const int tid = threadIdx.x, lane = tid & 63, wid = tid >> 6;
    const int b = blockIdx.x;
    const long long t = (long long)b * BLK + tid;

    float4 d[CH];
    bool full;
    float4 q = chunk_quats(al, t, T, nchunk, d, full);

    // In-register wave inclusive scan; wave aggregate to LDS.
    float4 v = wave_scan_incl(q, lane);
    if (lane == 63) sW[wid] = v;

    // Wave 0: spine prefix over A[0..b) in fixed 64-wide windows, high -> low.
    if (tid < 64) {
        float4 sp = qid();
        if (b > 0) {
            int top = b - 1;
            int base = (top >> 6) << 6;
            for (;;) {
                int j = base + lane;
                float4 contrib = (j <= top) ? A[j] : qid();
                float4 wp = wave_prod_desc(contrib);   // lane0: A[min(top,base+63)]@...@A[base]
                sp = qmul(sp, wp);                     // accumulate later (higher) windows on the left
                if (base == 0) break;
                top = base - 1;
                base -= 64;
            }
        }
        if (lane == 0) {
            // q0 from J0 = [[w - i v1, -v3 - i v2],[v3 - i v2, w + i v1]]
            float4 q0 = make_float4(j0re[0], -j0im[0], -j0im[1], -j0re[1]);
            sexcl = qnorm(qmul(sp, q0));
        }
    }
    __syncthreads();

    // Wave-exclusive prefix within block: P = sW[wid-1]@...@sW[0].
    float4 P = qid();
    for (int w = 0; w < wid; ++w) P = qmul(sW[w], P);
    float4 vprev = shfl_up4(v, 1);
    float4 Xv = (lane == 0) ? P : qmul(vprev, P);
    float4 run = qmul(Xv, sexcl);
    if (t < nchunk)
        apply_and_store(d, run, full, t, T, sre, sim, outf);
}

// Zero-workspace fallback: one block walks the whole sequence in segments.
__global__ void __launch_bounds__(BLK) pmd_mono(
    const float* __restrict__ al, const float* __restrict__ sre,
    const float* __restrict__ sim, const float* __restrict__ j0re,
    const float* __restrict__ j0im, float* __restrict__ outf, long long T) {
    __shared__ float4 sW[BLK / 64];
    __shared__ float4 sbase;
    const int tid = threadIdx.x, lane = tid & 63, wid = tid >> 6;
    if (tid == 0)
        sbase = make_float4(j0re[0], -j0im[0], -j0im[1], -j0re[1]);
    __syncthreads();
    const long long nchunk = (T + CH - 1) / CH;
    for (long long c0 = 0; c0 < nchunk; c0 += BLK) {
        const long long t = c0 + tid;
        float4 d[CH];
        bool full;
        float4 q = chunk_quats(al, t, T, nchunk, d, full);
        float4 v = wave_scan_incl(q, lane);
        if (lane == 63) sW[wid] = v;
        __syncthreads();
        float4 P = qid();
        for (int w = 0; w < wid; ++w) P = qmul(sW[w], P);
        float4 vprev = shfl_up4(v, 1);
        float4 Xv = (lane == 0) ? P : qmul(vprev, P);
        float4 base = sbase;
        __syncthreads();
        if (tid == BLK - 1) sbase = qnorm(qmul(qmul(v, P), base));
        if (t < nchunk) {
            float4 run = qmul(Xv, base);
            apply_and_store(d, run, full, t, T, sre, sim, outf);
        }
        __syncthreads();
    }
}

extern "C" void kernel_launch(void* const* d_in, const int* in_sizes, int n_in,
                              void* d_out, int out_size, void* d_ws, size_t ws_size,
                              hipStream_t stream) {
    const float* sre  = (const float*)d_in[0];
    const float* sim  = (const float*)d_in[1];
    const float* al   = (const float*)d_in[2];
    const float* j0re = (const float*)d_in[3];
    const float* j0im = (const float*)d_in[4];
    float* outf = (float*)d_out;   // f32 out, real parts [T,2]
    long long T = (long long)in_sizes[2] / 3;
    if (T <= 0) return;

    long long nchunk = (T + CH - 1) / CH;
    long long nblkLL = (nchunk + BLK - 1) / BLK;
    size_t need = (size_t)nblkLL * sizeof(float4);

    if (ws_size >= need && nblkLL <= 0x7fffffff) {
        int nblk = (int)nblkLL;
        float4* A = (float4*)d_ws;
        pmd_k1<<<nblk, BLK, 0, stream>>>(al, A, T, nchunk);
        pmd_k2<<<nblk, BLK, 0, stream>>>(al, sre, sim, j0re, j0im, A, outf, T, nchunk);
    } else {
        pmd_mono<<<1, BLK, 0, stream>>>(al, sre, sim, j0re, j0im, outf, T);
    }
}